// Round 4
// baseline (880.597 us; speedup 1.0000x reference)
//
#include <hip/hip_runtime.h>
#include <hip/hip_bf16.h>
#include <cstdint>
#include <cstddef>

#define NATOMS 8192
#define DIM 32
#define NSEQ 4096
#define KSPLIT 16
#define BM 256
#define BK 32
#define KPB (NATOMS / KSPLIT)   // 512
#define NT (KPB / BK)           // 16 (GEMM1)
#define BK2 64
#define NT2 (KPB / BK2)         // 8  (GEMM2/3)

typedef __attribute__((address_space(1))) const void GV;
typedef __attribute__((address_space(3))) void LV;
using bf16x8 = __attribute__((ext_vector_type(8))) short;
using f32x4  = __attribute__((ext_vector_type(4))) float;

__device__ __forceinline__ void async16(void* lds, const void* g) {
  __builtin_amdgcn_global_load_lds((GV*)g, (LV*)lds, 16, 0, 0);
}
__device__ __forceinline__ uint32_t pkbf(float lo, float hi) {
  union { __hip_bfloat16 b[2]; uint32_t u; } v;
  v.b[0] = __float2bfloat16(lo);
  v.b[1] = __float2bfloat16(hi);
  return v.u;
}

// ---------------------------------------------------------------------------
// GEMM1: P = A(fp32) @ h, fp32 fmac path (round-3 structure), PLUS fused
// conversion of the A tile to bf16 (each element converted exactly once).
// P layout: row-major [ks][8192][32].
// ---------------------------------------------------------------------------
__global__ __launch_bounds__(256, 2)
void cpi_gemm_cv(const float* __restrict__ A, const float* __restrict__ h,
                 float* __restrict__ P, ushort* __restrict__ Abf) {
  __shared__ float Ab[2][BM * BK];   // 64 KiB, XOR-swizzled 16B chunks
  __shared__ float Hb[2][BK * DIM];  // 8 KiB, linear

  const int tid  = threadIdx.x;
  const int wave = tid >> 6;
  const int lane = tid & 63;
  const int rb   = blockIdx.x & 31;
  const int ks   = blockIdx.x >> 5;
  const int row0 = rb * BM;
  const int k0   = ks * KPB;

  float acc[4][8];
#pragma unroll
  for (int j = 0; j < 4; ++j)
#pragma unroll
    for (int c = 0; c < 8; ++c) acc[j][c] = 0.f;

  auto stage = [&](int buf, int t) {
    const int kb = k0 + t * BK;
#pragma unroll
    for (int i = 0; i < 8; ++i) {
      const int D = (wave * 8 + i) * 64 + lane;  // 16B chunk 0..2047
      const int r = D >> 3;
      const int c = D & 7;
      const float* src =
          A + (size_t)(row0 + r) * NATOMS + kb + ((c ^ (r & 7)) << 2);
      async16(&Ab[buf][(wave * 8 + i) * 256], src);
    }
    const float* hsrc = h + (size_t)kb * DIM + (wave * 64 + lane) * 4;
    async16(&Hb[buf][wave * 256], hsrc);
  };

  stage(0, 0);
  asm volatile("s_waitcnt vmcnt(0)" ::: "memory");
  __syncthreads();

  int cur = 0;
  const int sb = lane & 7;
#pragma unroll 1
  for (int t = 0; t < NT; ++t) {
    if (t + 1 < NT) stage(cur ^ 1, t + 1);

    const float* Ac = &Ab[cur][0];
    const float* Hc = &Hb[cur][0] + wave * 8;
    uint32_t pk[4][4];

#pragma unroll
    for (int k4 = 0; k4 < 8; ++k4) {
      float4 h0[4], h1[4];
#pragma unroll
      for (int kk = 0; kk < 4; ++kk) {
        const float* hp = Hc + (k4 * 4 + kk) * DIM;
        h0[kk] = *(const float4*)hp;
        h1[kk] = *(const float4*)(hp + 4);
      }

      const int slot = k4 ^ sb;
      float4 a[4];
#pragma unroll
      for (int j = 0; j < 4; ++j)
        a[j] = *(const float4*)(Ac + (lane + 64 * j) * BK + slot * 4);

      // fused bf16 conversion: wave w owns k-slice [kb+8w, kb+8w+8)
      if ((k4 >> 1) == wave) {
        const int half = k4 & 1;
#pragma unroll
        for (int j = 0; j < 4; ++j) {
          pk[j][half * 2]     = pkbf(a[j].x, a[j].y);
          pk[j][half * 2 + 1] = pkbf(a[j].z, a[j].w);
        }
      }

#pragma unroll
      for (int j = 0; j < 4; ++j) {
#pragma unroll
        for (int kk = 0; kk < 4; ++kk) {
          const float av = (kk == 0) ? a[j].x
                         : (kk == 1) ? a[j].y
                         : (kk == 2) ? a[j].z : a[j].w;
          acc[j][0] += av * h0[kk].x;
          acc[j][1] += av * h0[kk].y;
          acc[j][2] += av * h0[kk].z;
          acc[j][3] += av * h0[kk].w;
          acc[j][4] += av * h1[kk].x;
          acc[j][5] += av * h1[kk].y;
          acc[j][6] += av * h1[kk].z;
          acc[j][7] += av * h1[kk].w;
        }
      }
    }

    // store this tile's bf16 A slice (4 rows x 8 k per thread)
    {
      const int kb = k0 + t * BK;
#pragma unroll
      for (int j = 0; j < 4; ++j) {
        uint4 u = make_uint4(pk[j][0], pk[j][1], pk[j][2], pk[j][3]);
        *(uint4*)(Abf + (size_t)(row0 + lane + 64 * j) * NATOMS + kb +
                  wave * 8) = u;
      }
    }

    asm volatile("s_waitcnt vmcnt(0)" ::: "memory");
    __syncthreads();
    cur ^= 1;
  }

  float* Pp = P + (size_t)ks * (NATOMS * DIM) + (size_t)row0 * DIM + wave * 8;
#pragma unroll
  for (int j = 0; j < 4; ++j) {
    const int r = lane + 64 * j;
    float4 v0 = make_float4(acc[j][0], acc[j][1], acc[j][2], acc[j][3]);
    float4 v1 = make_float4(acc[j][4], acc[j][5], acc[j][6], acc[j][7]);
    *(float4*)(Pp + (size_t)r * DIM) = v0;
    *(float4*)(Pp + (size_t)r * DIM + 4) = v1;
  }
}

// ---------------------------------------------------------------------------
// GEMM2/3: P = A(bf16) @ h(bf16, pre-transposed hT[32][8192]) via MFMA.
// P layout: fragment-native, slice stride 262144 floats per ks.
// ---------------------------------------------------------------------------
__global__ __launch_bounds__(256, 2)
void cpi_gemm_bf(const ushort* __restrict__ Abf, const ushort* __restrict__ hT,
                 float* __restrict__ P) {
  __shared__ ushort Ab[2][BM * BK2];   // 32 KB each, XOR-swizzled
  __shared__ ushort Hb[2][DIM * BK2];  // 4 KB each, XOR-swizzled

  const int tid  = threadIdx.x;
  const int wave = tid >> 6;
  const int lane = tid & 63;
  const int rb   = blockIdx.x & 31;
  const int ks   = blockIdx.x >> 5;
  const int row0 = rb * BM;
  const int k0   = ks * KPB;
  const int l15  = lane & 15;
  const int l4   = lane >> 4;

  f32x4 acc[4][2];
#pragma unroll
  for (int rt = 0; rt < 4; ++rt)
#pragma unroll
    for (int ct = 0; ct < 2; ++ct) acc[rt][ct] = {0.f, 0.f, 0.f, 0.f};

  auto stage = [&](int buf, int t) {
    const int kb = k0 + t * BK2;
#pragma unroll
    for (int i = 0; i < 8; ++i) {
      const int D = (wave * 8 + i) * 64 + lane;  // 16B chunk 0..2047
      const int r = D >> 3;                      // row (8 chunks/row)
      const int c = D & 7;
      const ushort* src =
          Abf + (size_t)(row0 + r) * NATOMS + kb + ((c ^ (r & 7)) << 3);
      async16(&Ab[buf][(wave * 8 + i) * 512], src);
    }
    const int D2 = wave * 64 + lane;  // 256 chunks of hT tile
    const int hc = D2 >> 3;
    const int hh = D2 & 7;
    const ushort* hsrc =
        hT + (size_t)hc * NATOMS + kb + ((hh ^ (hc & 7)) << 3);
    async16(&Hb[buf][wave * 512], hsrc);
  };

  stage(0, 0);
  asm volatile("s_waitcnt vmcnt(0)" ::: "memory");
  __syncthreads();

  int cur = 0;
#pragma unroll 1
  for (int t = 0; t < NT2; ++t) {
    if (t + 1 < NT2) stage(cur ^ 1, t + 1);

    const ushort* Ac = &Ab[cur][0];
    const ushort* Hc = &Hb[cur][0];
#pragma unroll
    for (int ks2 = 0; ks2 < 2; ++ks2) {
      const int g = ks2 * 4 + l4;  // global 16B chunk (8 bf16 k-values)
      bf16x8 av[4], bv[2];
#pragma unroll
      for (int rt = 0; rt < 4; ++rt) {
        const int r = wave * 64 + rt * 16 + l15;
        av[rt] = *(const bf16x8*)(Ac + r * 64 + ((g ^ (r & 7)) << 3));
      }
#pragma unroll
      for (int ct = 0; ct < 2; ++ct) {
        const int c = ct * 16 + l15;
        bv[ct] = *(const bf16x8*)(Hc + c * 64 + ((g ^ (c & 7)) << 3));
      }
#pragma unroll
      for (int rt = 0; rt < 4; ++rt)
#pragma unroll
        for (int ct = 0; ct < 2; ++ct)
          acc[rt][ct] = __builtin_amdgcn_mfma_f32_16x16x32_bf16(
              av[rt], bv[ct], acc[rt][ct], 0, 0, 0);
    }

    asm volatile("s_waitcnt vmcnt(0)" ::: "memory");
    __syncthreads();
    cur ^= 1;
  }

  // fragment-native store: 1024B contiguous per (rt,ct) subtile
  float* Pp = P + ((((size_t)ks * 32 + rb) * 4 + wave) * 8) * 256;
#pragma unroll
  for (int rt = 0; rt < 4; ++rt)
#pragma unroll
    for (int ct = 0; ct < 2; ++ct)
      *(f32x4*)(Pp + (rt * 2 + ct) * 256 + lane * 4) = acc[rt][ct];
}

// ---------------------------------------------------------------------------
// Gather xs = emb_fp[fingerprints] -> out, and h0 = relu(xs@W0 + b0) (fp32)
// ---------------------------------------------------------------------------
__global__ __launch_bounds__(256)
void cpi_gather_h(const int* __restrict__ fp, const float* __restrict__ embfp,
                  const float* __restrict__ W, const float* __restrict__ b,
                  float* __restrict__ xs, float* __restrict__ hout) {
  __shared__ float xsl[8][DIM];
  __shared__ float Wl[DIM][DIM];
  const int tid = threadIdx.x;
  const int col = tid & 31;
  const int r8  = tid >> 5;
  const int row = blockIdx.x * 8 + r8;
  const int f   = fp[row];
  const float v = embfp[(size_t)f * DIM + col];
  xs[(size_t)row * DIM + col] = v;
  xsl[r8][col] = v;
#pragma unroll
  for (int i = 0; i < 4; ++i) {
    const int idx = tid + i * 256;
    ((float*)Wl)[idx] = W[idx];
  }
  __syncthreads();
  float a = b[col];
#pragma unroll
  for (int d = 0; d < DIM; ++d) a += xsl[r8][d] * Wl[d][col];
  hout[(size_t)row * DIM + col] = fmaxf(a, 0.f);
}

// ---------------------------------------------------------------------------
// xs += sum_ks P[ks] (frag or row-major layout); optionally
// hT[col][row] = bf16(relu(xs@W + b)) for the next (MFMA) layer
// ---------------------------------------------------------------------------
__global__ __launch_bounds__(256)
void cpi_reduce_h(const float* __restrict__ P, const float* __restrict__ W,
                  const float* __restrict__ b, float* __restrict__ xs,
                  ushort* __restrict__ hT, const int compute_h,
                  const int frag) {
  __shared__ float xsl[8][DIM];
  __shared__ float Wl[DIM][DIM];
  const int tid = threadIdx.x;
  const int col = tid & 31;
  const int r8  = tid >> 5;
  const int row = blockIdx.x * 8 + r8;
  const size_t off = (size_t)row * DIM + col;
  float s = xs[off];
  if (frag) {
    const int rbv = row >> 8, rr = row & 255;
    const int w = rr >> 6, rr6 = rr & 63;
    const int rt = rr6 >> 4, q4 = (rr6 >> 2) & 3, i = rr6 & 3;
    const int ct = col >> 4, lane = q4 * 16 + (col & 15);
    const int base = ((rbv * 4 + w) * 8 + rt * 2 + ct) * 256 + lane * 4 + i;
#pragma unroll
    for (int k = 0; k < KSPLIT; ++k) s += P[(size_t)k * (NATOMS * DIM) + base];
  } else {
#pragma unroll
    for (int k = 0; k < KSPLIT; ++k) s += P[(size_t)k * (NATOMS * DIM) + off];
  }
  xs[off] = s;
  if (compute_h) {  // uniform branch
    xsl[r8][col] = s;
#pragma unroll
    for (int i = 0; i < 4; ++i) {
      const int idx = tid + i * 256;
      ((float*)Wl)[idx] = W[idx];
    }
    __syncthreads();
    float a = b[col];
#pragma unroll
    for (int d = 0; d < DIM; ++d) a += xsl[r8][d] * Wl[d][col];
    union { __hip_bfloat16 bb; ushort u; } cv;
    cv.bb = __float2bfloat16(fmaxf(a, 0.f));
    hT[(size_t)col * NATOMS + row] = cv.u;  // transposed bf16 h
  }
}

// ---------------------------------------------------------------------------
// word_vectors = emb_word[words]
// ---------------------------------------------------------------------------
__global__ __launch_bounds__(256)
void cpi_words(const int* __restrict__ words, const float* __restrict__ embw,
               float* __restrict__ out) {
  const int i = blockIdx.x * 256 + threadIdx.x;
  const int s = i >> 5;
  const int c = i & 31;
  out[i] = embw[(size_t)words[s] * DIM + c];
}

extern "C" void kernel_launch(void* const* d_in, const int* in_sizes, int n_in,
                              void* d_out, int out_size, void* d_ws, size_t ws_size,
                              hipStream_t stream) {
  const int*   fp    = (const int*)d_in[0];
  const float* adj   = (const float*)d_in[1];
  const int*   words = (const int*)d_in[2];
  const float* embfp = (const float*)d_in[3];
  const float* embw  = (const float*)d_in[4];
  const float* Wg    = (const float*)d_in[5];
  const float* bg    = (const float*)d_in[6];

  float* out = (float*)d_out;
  float* xs  = out;                 // [8192*32] final compound_vector
  float* wv  = out + NATOMS * DIM;  // [4096*32] word vectors

  float*  h   = (float*)d_ws;                              // 1 MB fp32 h0
  float*  P   = h + NATOMS * DIM;                          // 16 MB partials
  ushort* Abf = (ushort*)(P + (size_t)KSPLIT * NATOMS * DIM);  // 128 MB bf16 A
  ushort* hT  = Abf + (size_t)NATOMS * NATOMS;             // 512 KB bf16 h^T

  cpi_words<<<dim3(NSEQ * DIM / 256), dim3(256), 0, stream>>>(words, embw, wv);
  cpi_gather_h<<<dim3(NATOMS / 8), dim3(256), 0, stream>>>(fp, embfp, Wg, bg,
                                                           xs, h);

  // layer 0: fp32 A, fused bf16 conversion
  cpi_gemm_cv<<<dim3(512), dim3(256), 0, stream>>>(adj, h, P, Abf);
  cpi_reduce_h<<<dim3(NATOMS / 8), dim3(256), 0, stream>>>(
      P, Wg + DIM * DIM, bg + DIM, xs, hT, 1, 0);

  // layer 1: bf16 MFMA
  cpi_gemm_bf<<<dim3(512), dim3(256), 0, stream>>>(Abf, hT, P);
  cpi_reduce_h<<<dim3(NATOMS / 8), dim3(256), 0, stream>>>(
      P, Wg + 2 * DIM * DIM, bg + 2 * DIM, xs, hT, 1, 1);

  // layer 2: bf16 MFMA
  cpi_gemm_bf<<<dim3(512), dim3(256), 0, stream>>>(Abf, hT, P);
  cpi_reduce_h<<<dim3(NATOMS / 8), dim3(256), 0, stream>>>(
      P, Wg, bg, xs, hT, 0, 1);
}

// Round 5
// 158.894 us; speedup vs baseline: 5.5420x; 5.5420x over previous
//
#include <hip/hip_runtime.h>
#include <hip/hip_bf16.h>
#include <cstdint>
#include <cstddef>

#define NATOMS 8192
#define DIM 32
#define NSEQ 4096
#define KSPLIT 16
#define BM 256
#define BK 32
#define KPB (NATOMS / KSPLIT)   // 512 k per block
#define NT (KPB / BK)           // 16 tiles

typedef __attribute__((address_space(1))) const void GV;
typedef __attribute__((address_space(3))) void LV;
using bf16x8 = __attribute__((ext_vector_type(8))) short;
using f32x4  = __attribute__((ext_vector_type(4))) float;

__device__ __forceinline__ void async16(void* lds, const void* g) {
  __builtin_amdgcn_global_load_lds((GV*)g, (LV*)lds, 16, 0, 0);
}
__device__ __forceinline__ uint32_t pkbf(float lo, float hi) {
  union { __hip_bfloat16 b[2]; uint32_t u; } v;
  v.b[0] = __float2bfloat16(lo);
  v.b[1] = __float2bfloat16(hi);
  return v.u;
}
union U8 { uint32_t u[4]; bf16x8 v; };

// bf16 tile image: per (ks,rb,t) tile of 256 rows x 32 k: row r = 64B = 4
// 16B slots; slot s holds k-chunk g = s ^ ((r>>1)&3). A wave storing av[rt]
// (lane -> row l15, k-chunk l4) covers a complete contiguous 1KB region.
__device__ __forceinline__ int aslot(int r, int g) { return g ^ ((r >> 1) & 3); }
__device__ __forceinline__ int hslot(int n, int g) { return g ^ ((n >> 1) & 3); }

// ---------------------------------------------------------------------------
// Layer-0 GEMM: P = A(fp32->bf16) @ hT, MFMA; also writes Abf tile image.
// ---------------------------------------------------------------------------
__global__ __launch_bounds__(256, 2)
void cpi_gemm1(const float* __restrict__ A, const ushort* __restrict__ hT,
               float* __restrict__ P, ushort* __restrict__ Abf) {
  __shared__ float  Ab[2][BM * BK];   // 64 KiB, 8-slot XOR-swizzled fp32
  __shared__ ushort Hb[2][DIM * BK];  // 4 KiB, 4-slot XOR-swizzled bf16

  const int tid  = threadIdx.x;
  const int wave = tid >> 6;
  const int lane = tid & 63;
  const int l15  = lane & 15;
  const int l4   = lane >> 4;
  const int rb   = blockIdx.x & 31;
  const int ks   = blockIdx.x >> 5;
  const int row0 = rb * BM;
  const int k0   = ks * KPB;

  f32x4 acc[4][2];
#pragma unroll
  for (int rt = 0; rt < 4; ++rt)
#pragma unroll
    for (int ct = 0; ct < 2; ++ct) acc[rt][ct] = {0.f, 0.f, 0.f, 0.f};

  auto stage = [&](int buf, int t) {
    const int kb = k0 + t * BK;
#pragma unroll
    for (int i = 0; i < 8; ++i) {
      const int D = (wave * 8 + i) * 64 + lane;  // fp32 16B chunk 0..2047
      const int r = D >> 3;
      const int c = D & 7;
      const float* src =
          A + (size_t)(row0 + r) * NATOMS + kb + ((c ^ (r & 7)) << 2);
      async16(&Ab[buf][(wave * 8 + i) * 256], src);
    }
    if (wave < 2) {  // h tile: 2KB = 128 chunks
      const int E = wave * 64 + lane;
      const int n = E >> 2;
      const int s = E & 3;
      const ushort* src = hT + (size_t)n * NATOMS + kb + (hslot(n, s) << 3);
      async16(&Hb[buf][wave * 512], src);
    }
  };

  stage(0, 0);
  asm volatile("s_waitcnt vmcnt(0)" ::: "memory");
  __syncthreads();

  int cur = 0;
#pragma unroll 1
  for (int t = 0; t < NT; ++t) {
    if (t + 1 < NT) stage(cur ^ 1, t + 1);

    const float*  Ac = &Ab[cur][0];
    const ushort* Hc = &Hb[cur][0];

    // A fragments: convert fp32 LDS -> bf16
    bf16x8 av[4];
#pragma unroll
    for (int rt = 0; rt < 4; ++rt) {
      const int r = wave * 64 + rt * 16 + l15;
      const float4 f0 =
          *(const float4*)(Ac + r * 32 + (((2 * l4) ^ (r & 7)) << 2));
      const float4 f1 =
          *(const float4*)(Ac + r * 32 + (((2 * l4 + 1) ^ (r & 7)) << 2));
      U8 u;
      u.u[0] = pkbf(f0.x, f0.y);
      u.u[1] = pkbf(f0.z, f0.w);
      u.u[2] = pkbf(f1.x, f1.y);
      u.u[3] = pkbf(f1.z, f1.w);
      av[rt] = u.v;
    }
    bf16x8 bv[2];
#pragma unroll
    for (int ct = 0; ct < 2; ++ct) {
      const int n = ct * 16 + l15;
      bv[ct] = *(const bf16x8*)(Hc + n * 32 + (hslot(n, l4) << 3));
    }

    // store bf16 tile image (each wave instruction = contiguous 1KB)
    ushort* Tb = Abf + (((size_t)ks * 32 + rb) * 16 + t) * (BM * BK);
#pragma unroll
    for (int rt = 0; rt < 4; ++rt) {
      const int r = wave * 64 + rt * 16 + l15;
      *(bf16x8*)(Tb + r * 32 + (aslot(r, l4) << 3)) = av[rt];
    }

#pragma unroll
    for (int rt = 0; rt < 4; ++rt)
#pragma unroll
      for (int ct = 0; ct < 2; ++ct)
        acc[rt][ct] = __builtin_amdgcn_mfma_f32_16x16x32_bf16(
            av[rt], bv[ct], acc[rt][ct], 0, 0, 0);

    asm volatile("s_waitcnt vmcnt(0)" ::: "memory");
    __syncthreads();
    cur ^= 1;
  }

  float* Pp = P + ((((size_t)ks * 32 + rb) * 4 + wave) * 8) * 256;
#pragma unroll
  for (int rt = 0; rt < 4; ++rt)
#pragma unroll
    for (int ct = 0; ct < 2; ++ct)
      *(f32x4*)(Pp + (rt * 2 + ct) * 256 + lane * 4) = acc[rt][ct];
}

// ---------------------------------------------------------------------------
// Layers 1/2 GEMM: P = Abf(bf16 tile image) @ hT, MFMA. Linear LDS copy.
// ---------------------------------------------------------------------------
__global__ __launch_bounds__(256, 4)
void cpi_gemm2(const ushort* __restrict__ Abf, const ushort* __restrict__ hT,
               float* __restrict__ P) {
  __shared__ ushort Ab[2][BM * BK];   // 16 KiB each (bf16)
  __shared__ ushort Hb[2][DIM * BK];  // 2 KiB each

  const int tid  = threadIdx.x;
  const int wave = tid >> 6;
  const int lane = tid & 63;
  const int l15  = lane & 15;
  const int l4   = lane >> 4;
  const int rb   = blockIdx.x & 31;
  const int ks   = blockIdx.x >> 5;
  const int k0   = ks * KPB;

  f32x4 acc[4][2];
#pragma unroll
  for (int rt = 0; rt < 4; ++rt)
#pragma unroll
    for (int ct = 0; ct < 2; ++ct) acc[rt][ct] = {0.f, 0.f, 0.f, 0.f};

  auto stage = [&](int buf, int t) {
    const ushort* Tb = Abf + (((size_t)ks * 32 + rb) * 16 + t) * (BM * BK);
#pragma unroll
    for (int i = 0; i < 4; ++i)  // 16KB linear copy
      async16(&Ab[buf][(wave * 4 + i) * 512],
              Tb + ((wave * 4 + i) * 64 + lane) * 8);
    if (wave < 2) {
      const int kb = k0 + t * BK;
      const int E = wave * 64 + lane;
      const int n = E >> 2;
      const int s = E & 3;
      const ushort* src = hT + (size_t)n * NATOMS + kb + (hslot(n, s) << 3);
      async16(&Hb[buf][wave * 512], src);
    }
  };

  stage(0, 0);
  asm volatile("s_waitcnt vmcnt(0)" ::: "memory");
  __syncthreads();

  int cur = 0;
#pragma unroll 1
  for (int t = 0; t < NT; ++t) {
    if (t + 1 < NT) stage(cur ^ 1, t + 1);

    const ushort* Ac = &Ab[cur][0];
    const ushort* Hc = &Hb[cur][0];

    bf16x8 av[4], bv[2];
#pragma unroll
    for (int rt = 0; rt < 4; ++rt) {
      const int r = wave * 64 + rt * 16 + l15;
      av[rt] = *(const bf16x8*)(Ac + r * 32 + (aslot(r, l4) << 3));
    }
#pragma unroll
    for (int ct = 0; ct < 2; ++ct) {
      const int n = ct * 16 + l15;
      bv[ct] = *(const bf16x8*)(Hc + n * 32 + (hslot(n, l4) << 3));
    }

#pragma unroll
    for (int rt = 0; rt < 4; ++rt)
#pragma unroll
      for (int ct = 0; ct < 2; ++ct)
        acc[rt][ct] = __builtin_amdgcn_mfma_f32_16x16x32_bf16(
            av[rt], bv[ct], acc[rt][ct], 0, 0, 0);

    asm volatile("s_waitcnt vmcnt(0)" ::: "memory");
    __syncthreads();
    cur ^= 1;
  }

  float* Pp = P + ((((size_t)ks * 32 + rb) * 4 + wave) * 8) * 256;
#pragma unroll
  for (int rt = 0; rt < 4; ++rt)
#pragma unroll
    for (int ct = 0; ct < 2; ++ct)
      *(f32x4*)(Pp + (rt * 2 + ct) * 256 + lane * 4) = acc[rt][ct];
}

// ---------------------------------------------------------------------------
// Gather xs = emb_fp[fingerprints] -> out, and hT = bf16(relu(xs@W0 + b0))
// ---------------------------------------------------------------------------
__global__ __launch_bounds__(256)
void cpi_gather_h(const int* __restrict__ fp, const float* __restrict__ embfp,
                  const float* __restrict__ W, const float* __restrict__ b,
                  float* __restrict__ xs, ushort* __restrict__ hT) {
  __shared__ float xsl[8][DIM];
  __shared__ float Wl[DIM][DIM];
  const int tid = threadIdx.x;
  const int col = tid & 31;
  const int r8  = tid >> 5;
  const int row = blockIdx.x * 8 + r8;
  const int f   = fp[row];
  const float v = embfp[(size_t)f * DIM + col];
  xs[(size_t)row * DIM + col] = v;
  xsl[r8][col] = v;
#pragma unroll
  for (int i = 0; i < 4; ++i) {
    const int idx = tid + i * 256;
    ((float*)Wl)[idx] = W[idx];
  }
  __syncthreads();
  float a = b[col];
#pragma unroll
  for (int d = 0; d < DIM; ++d) a += xsl[r8][d] * Wl[d][col];
  union { __hip_bfloat16 bb; ushort u; } cv;
  cv.bb = __float2bfloat16(fmaxf(a, 0.f));
  hT[(size_t)col * NATOMS + row] = cv.u;
}

// ---------------------------------------------------------------------------
// xs += sum_ks P[ks] (fragment-native layout); optionally
// hT[col][row] = bf16(relu(xs@W + b)) for the next layer
// ---------------------------------------------------------------------------
__global__ __launch_bounds__(256)
void cpi_reduce_h(const float* __restrict__ P, const float* __restrict__ W,
                  const float* __restrict__ b, float* __restrict__ xs,
                  ushort* __restrict__ hT, const int compute_h) {
  __shared__ float xsl[8][DIM];
  __shared__ float Wl[DIM][DIM];
  const int tid = threadIdx.x;
  const int col = tid & 31;
  const int r8  = tid >> 5;
  const int row = blockIdx.x * 8 + r8;
  const size_t off = (size_t)row * DIM + col;
  float s = xs[off];
  {
    const int rbv = row >> 8, rr = row & 255;
    const int w = rr >> 6, rr6 = rr & 63;
    const int rt = rr6 >> 4, q4 = (rr6 >> 2) & 3, i = rr6 & 3;
    const int ct = col >> 4, lane = q4 * 16 + (col & 15);
    const int base = ((rbv * 4 + w) * 8 + rt * 2 + ct) * 256 + lane * 4 + i;
#pragma unroll
    for (int k = 0; k < KSPLIT; ++k) s += P[(size_t)k * (NATOMS * DIM) + base];
  }
  xs[off] = s;
  if (compute_h) {  // uniform branch
    xsl[r8][col] = s;
#pragma unroll
    for (int i = 0; i < 4; ++i) {
      const int idx = tid + i * 256;
      ((float*)Wl)[idx] = W[idx];
    }
    __syncthreads();
    float a = b[col];
#pragma unroll
    for (int d = 0; d < DIM; ++d) a += xsl[r8][d] * Wl[d][col];
    union { __hip_bfloat16 bb; ushort u; } cv;
    cv.bb = __float2bfloat16(fmaxf(a, 0.f));
    hT[(size_t)col * NATOMS + row] = cv.u;
  }
}

// ---------------------------------------------------------------------------
// word_vectors = emb_word[words]
// ---------------------------------------------------------------------------
__global__ __launch_bounds__(256)
void cpi_words(const int* __restrict__ words, const float* __restrict__ embw,
               float* __restrict__ out) {
  const int i = blockIdx.x * 256 + threadIdx.x;
  const int s = i >> 5;
  const int c = i & 31;
  out[i] = embw[(size_t)words[s] * DIM + c];
}

extern "C" void kernel_launch(void* const* d_in, const int* in_sizes, int n_in,
                              void* d_out, int out_size, void* d_ws, size_t ws_size,
                              hipStream_t stream) {
  const int*   fp    = (const int*)d_in[0];
  const float* adj   = (const float*)d_in[1];
  const int*   words = (const int*)d_in[2];
  const float* embfp = (const float*)d_in[3];
  const float* embw  = (const float*)d_in[4];
  const float* Wg    = (const float*)d_in[5];
  const float* bg    = (const float*)d_in[6];

  float* out = (float*)d_out;
  float* xs  = out;                 // [8192*32] final compound_vector
  float* wv  = out + NATOMS * DIM;  // [4096*32] word vectors

  float*  P   = (float*)d_ws;                               // 16 MB partials
  ushort* Abf = (ushort*)(P + (size_t)KSPLIT * NATOMS * DIM);  // 128 MB bf16 A
  ushort* hT  = Abf + (size_t)NATOMS * NATOMS;              // 512 KB bf16 h^T

  cpi_words<<<dim3(NSEQ * DIM / 256), dim3(256), 0, stream>>>(words, embw, wv);
  cpi_gather_h<<<dim3(NATOMS / 8), dim3(256), 0, stream>>>(fp, embfp, Wg, bg,
                                                           xs, hT);

  // layer 0: fp32 A staged, bf16 MFMA, emits Abf tile image
  cpi_gemm1<<<dim3(512), dim3(256), 0, stream>>>(adj, hT, P, Abf);
  cpi_reduce_h<<<dim3(NATOMS / 8), dim3(256), 0, stream>>>(
      P, Wg + DIM * DIM, bg + DIM, xs, hT, 1);

  // layer 1: bf16 tile-image MFMA
  cpi_gemm2<<<dim3(512), dim3(256), 0, stream>>>(Abf, hT, P);
  cpi_reduce_h<<<dim3(NATOMS / 8), dim3(256), 0, stream>>>(
      P, Wg + 2 * DIM * DIM, bg + 2 * DIM, xs, hT, 1);

  // layer 2: bf16 tile-image MFMA
  cpi_gemm2<<<dim3(512), dim3(256), 0, stream>>>(Abf, hT, P);
  cpi_reduce_h<<<dim3(NATOMS / 8), dim3(256), 0, stream>>>(
      P, Wg, bg, xs, hT, 0);
}

// Round 6
// 144.396 us; speedup vs baseline: 6.0985x; 1.1004x over previous
//
#include <hip/hip_runtime.h>
#include <hip/hip_bf16.h>
#include <cstdint>
#include <cstddef>

#define NATOMS 8192
#define DIM 32
#define NSEQ 4096
#define KSPLIT 16
#define BM 256
#define BK 32
#define KPB (NATOMS / KSPLIT)   // 512 k per block
#define NT (KPB / BK)           // 16 tiles

typedef __attribute__((address_space(1))) const void GV;
typedef __attribute__((address_space(3))) void LV;
using bf16x8 = __attribute__((ext_vector_type(8))) short;
using f32x4  = __attribute__((ext_vector_type(4))) float;

__device__ __forceinline__ void async16(void* lds, const void* g) {
  __builtin_amdgcn_global_load_lds((GV*)g, (LV*)lds, 16, 0, 0);
}
// aux=2 -> NT (non-temporal) on gfx940+ CPol: streaming data, minimize cache
// retention so the 256MB fp32 A pass doesn't evict Abf from Infinity Cache.
__device__ __forceinline__ void async16nt(void* lds, const void* g) {
  __builtin_amdgcn_global_load_lds((GV*)g, (LV*)lds, 16, 0, 2);
}
__device__ __forceinline__ uint32_t pkbf(float lo, float hi) {
  union { __hip_bfloat16 b[2]; uint32_t u; } v;
  v.b[0] = __float2bfloat16(lo);
  v.b[1] = __float2bfloat16(hi);
  return v.u;
}
union U8 { uint32_t u[4]; bf16x8 v; };

// bf16 tile image: per (ks,rb,t) tile of 256 rows x 32 k: row r = 64B = 4
// 16B slots; slot s holds k-chunk g = s ^ ((r>>1)&3). A wave storing av[rt]
// (lane -> row l15, k-chunk l4) covers a complete contiguous 1KB region.
__device__ __forceinline__ int aslot(int r, int g) { return g ^ ((r >> 1) & 3); }
__device__ __forceinline__ int hslot(int n, int g) { return g ^ ((n >> 1) & 3); }

// ---------------------------------------------------------------------------
// Layer-0 GEMM: P = A(fp32->bf16) @ hT, MFMA; also writes Abf tile image.
// ---------------------------------------------------------------------------
__global__ __launch_bounds__(256, 2)
void cpi_gemm1(const float* __restrict__ A, const ushort* __restrict__ hT,
               float* __restrict__ P, ushort* __restrict__ Abf) {
  __shared__ float  Ab[2][BM * BK];   // 64 KiB, 8-slot XOR-swizzled fp32
  __shared__ ushort Hb[2][DIM * BK];  // 4 KiB, 4-slot XOR-swizzled bf16

  const int tid  = threadIdx.x;
  const int wave = tid >> 6;
  const int lane = tid & 63;
  const int l15  = lane & 15;
  const int l4   = lane >> 4;
  const int rb   = blockIdx.x & 31;
  const int ks   = blockIdx.x >> 5;
  const int row0 = rb * BM;
  const int k0   = ks * KPB;

  f32x4 acc[4][2];
#pragma unroll
  for (int rt = 0; rt < 4; ++rt)
#pragma unroll
    for (int ct = 0; ct < 2; ++ct) acc[rt][ct] = {0.f, 0.f, 0.f, 0.f};

  auto stage = [&](int buf, int t) {
    const int kb = k0 + t * BK;
#pragma unroll
    for (int i = 0; i < 8; ++i) {
      const int D = (wave * 8 + i) * 64 + lane;  // fp32 16B chunk 0..2047
      const int r = D >> 3;
      const int c = D & 7;
      const float* src =
          A + (size_t)(row0 + r) * NATOMS + kb + ((c ^ (r & 7)) << 2);
      async16nt(&Ab[buf][(wave * 8 + i) * 256], src);  // NT: dead after read
    }
    if (wave < 2) {  // h tile: 2KB = 128 chunks
      const int E = wave * 64 + lane;
      const int n = E >> 2;
      const int s = E & 3;
      const ushort* src = hT + (size_t)n * NATOMS + kb + (hslot(n, s) << 3);
      async16(&Hb[buf][wave * 512], src);
    }
  };

  stage(0, 0);
  asm volatile("s_waitcnt vmcnt(0)" ::: "memory");
  __syncthreads();

  int cur = 0;
#pragma unroll 1
  for (int t = 0; t < NT; ++t) {
    if (t + 1 < NT) stage(cur ^ 1, t + 1);

    const float*  Ac = &Ab[cur][0];
    const ushort* Hc = &Hb[cur][0];

    // A fragments: convert fp32 LDS -> bf16
    bf16x8 av[4];
#pragma unroll
    for (int rt = 0; rt < 4; ++rt) {
      const int r = wave * 64 + rt * 16 + l15;
      const float4 f0 =
          *(const float4*)(Ac + r * 32 + (((2 * l4) ^ (r & 7)) << 2));
      const float4 f1 =
          *(const float4*)(Ac + r * 32 + (((2 * l4 + 1) ^ (r & 7)) << 2));
      U8 u;
      u.u[0] = pkbf(f0.x, f0.y);
      u.u[1] = pkbf(f0.z, f0.w);
      u.u[2] = pkbf(f1.x, f1.y);
      u.u[3] = pkbf(f1.z, f1.w);
      av[rt] = u.v;
    }
    bf16x8 bv[2];
#pragma unroll
    for (int ct = 0; ct < 2; ++ct) {
      const int n = ct * 16 + l15;
      bv[ct] = *(const bf16x8*)(Hc + n * 32 + (hslot(n, l4) << 3));
    }

    // store bf16 tile image (each wave instruction = contiguous 1KB);
    // stays in L3 (default policy) for gemm2/gemm3.
    ushort* Tb = Abf + (((size_t)ks * 32 + rb) * 16 + t) * (BM * BK);
#pragma unroll
    for (int rt = 0; rt < 4; ++rt) {
      const int r = wave * 64 + rt * 16 + l15;
      *(bf16x8*)(Tb + r * 32 + (aslot(r, l4) << 3)) = av[rt];
    }

#pragma unroll
    for (int rt = 0; rt < 4; ++rt)
#pragma unroll
      for (int ct = 0; ct < 2; ++ct)
        acc[rt][ct] = __builtin_amdgcn_mfma_f32_16x16x32_bf16(
            av[rt], bv[ct], acc[rt][ct], 0, 0, 0);

    // vmcnt(4): the 4 Abf stores are the newest FIFO entries; depth-4 wait
    // retires all 9 prefetch loads without stalling on store acks.
    asm volatile("s_waitcnt vmcnt(4)" ::: "memory");
    __syncthreads();
    cur ^= 1;
  }

  float* Pp = P + ((((size_t)ks * 32 + rb) * 4 + wave) * 8) * 256;
#pragma unroll
  for (int rt = 0; rt < 4; ++rt)
#pragma unroll
    for (int ct = 0; ct < 2; ++ct)
      *(f32x4*)(Pp + (rt * 2 + ct) * 256 + lane * 4) = acc[rt][ct];
}

// ---------------------------------------------------------------------------
// Layers 1/2 GEMM: P = Abf(bf16 tile image) @ hT, MFMA. Linear LDS copy.
// ---------------------------------------------------------------------------
__global__ __launch_bounds__(256, 4)
void cpi_gemm2(const ushort* __restrict__ Abf, const ushort* __restrict__ hT,
               float* __restrict__ P) {
  __shared__ ushort Ab[2][BM * BK];   // 16 KiB each (bf16)
  __shared__ ushort Hb[2][DIM * BK];  // 2 KiB each

  const int tid  = threadIdx.x;
  const int wave = tid >> 6;
  const int lane = tid & 63;
  const int l15  = lane & 15;
  const int l4   = lane >> 4;
  const int rb   = blockIdx.x & 31;
  const int ks   = blockIdx.x >> 5;
  const int k0   = ks * KPB;

  f32x4 acc[4][2];
#pragma unroll
  for (int rt = 0; rt < 4; ++rt)
#pragma unroll
    for (int ct = 0; ct < 2; ++ct) acc[rt][ct] = {0.f, 0.f, 0.f, 0.f};

  auto stage = [&](int buf, int t) {
    const ushort* Tb = Abf + (((size_t)ks * 32 + rb) * 16 + t) * (BM * BK);
#pragma unroll
    for (int i = 0; i < 4; ++i)  // 16KB linear copy
      async16(&Ab[buf][(wave * 4 + i) * 512],
              Tb + ((wave * 4 + i) * 64 + lane) * 8);
    if (wave < 2) {
      const int kb = k0 + t * BK;
      const int E = wave * 64 + lane;
      const int n = E >> 2;
      const int s = E & 3;
      const ushort* src = hT + (size_t)n * NATOMS + kb + (hslot(n, s) << 3);
      async16(&Hb[buf][wave * 512], src);
    }
  };

  stage(0, 0);
  asm volatile("s_waitcnt vmcnt(0)" ::: "memory");
  __syncthreads();

  int cur = 0;
#pragma unroll 1
  for (int t = 0; t < NT; ++t) {
    if (t + 1 < NT) stage(cur ^ 1, t + 1);

    const ushort* Ac = &Ab[cur][0];
    const ushort* Hc = &Hb[cur][0];

    bf16x8 av[4], bv[2];
#pragma unroll
    for (int rt = 0; rt < 4; ++rt) {
      const int r = wave * 64 + rt * 16 + l15;
      av[rt] = *(const bf16x8*)(Ac + r * 32 + (aslot(r, l4) << 3));
    }
#pragma unroll
    for (int ct = 0; ct < 2; ++ct) {
      const int n = ct * 16 + l15;
      bv[ct] = *(const bf16x8*)(Hc + n * 32 + (hslot(n, l4) << 3));
    }

#pragma unroll
    for (int rt = 0; rt < 4; ++rt)
#pragma unroll
      for (int ct = 0; ct < 2; ++ct)
        acc[rt][ct] = __builtin_amdgcn_mfma_f32_16x16x32_bf16(
            av[rt], bv[ct], acc[rt][ct], 0, 0, 0);

    asm volatile("s_waitcnt vmcnt(0)" ::: "memory");
    __syncthreads();
    cur ^= 1;
  }

  float* Pp = P + ((((size_t)ks * 32 + rb) * 4 + wave) * 8) * 256;
#pragma unroll
  for (int rt = 0; rt < 4; ++rt)
#pragma unroll
    for (int ct = 0; ct < 2; ++ct)
      *(f32x4*)(Pp + (rt * 2 + ct) * 256 + lane * 4) = acc[rt][ct];
}

// ---------------------------------------------------------------------------
// Front kernel: blocks [0,1024): xs = emb_fp[fp] -> out, hT = bf16(relu(
// xs@W0+b0)); blocks [1024,1536): word_vectors = emb_word[words].
// ---------------------------------------------------------------------------
__global__ __launch_bounds__(256)
void cpi_front(const int* __restrict__ fp, const float* __restrict__ embfp,
               const float* __restrict__ W, const float* __restrict__ b,
               float* __restrict__ xs, ushort* __restrict__ hT,
               const int* __restrict__ words, const float* __restrict__ embw,
               float* __restrict__ wout) {
  if (blockIdx.x >= NATOMS / 8) {  // words part (block-uniform branch)
    const int i = (blockIdx.x - NATOMS / 8) * 256 + threadIdx.x;
    wout[i] = embw[(size_t)words[i >> 5] * DIM + (i & 31)];
    return;
  }
  __shared__ float xsl[8][DIM];
  __shared__ float Wl[DIM][DIM];
  const int tid = threadIdx.x;
  const int col = tid & 31;
  const int r8  = tid >> 5;
  const int row = blockIdx.x * 8 + r8;
  const int f   = fp[row];
  const float v = embfp[(size_t)f * DIM + col];
  xs[(size_t)row * DIM + col] = v;
  xsl[r8][col] = v;
#pragma unroll
  for (int i = 0; i < 4; ++i) {
    const int idx = tid + i * 256;
    ((float*)Wl)[idx] = W[idx];
  }
  __syncthreads();
  float a = b[col];
#pragma unroll
  for (int d = 0; d < DIM; ++d) a += xsl[r8][d] * Wl[d][col];
  union { __hip_bfloat16 bb; ushort u; } cv;
  cv.bb = __float2bfloat16(fmaxf(a, 0.f));
  hT[(size_t)col * NATOMS + row] = cv.u;
}

// ---------------------------------------------------------------------------
// xs += sum_ks P[ks] (fragment-native layout, NT loads: P dead after);
// optionally hT[col][row] = bf16(relu(xs@W + b)) for the next layer
// ---------------------------------------------------------------------------
__global__ __launch_bounds__(256)
void cpi_reduce_h(const float* __restrict__ P, const float* __restrict__ W,
                  const float* __restrict__ b, float* __restrict__ xs,
                  ushort* __restrict__ hT, const int compute_h) {
  __shared__ float xsl[8][DIM];
  __shared__ float Wl[DIM][DIM];
  const int tid = threadIdx.x;
  const int col = tid & 31;
  const int r8  = tid >> 5;
  const int row = blockIdx.x * 8 + r8;
  const size_t off = (size_t)row * DIM + col;
  float s = xs[off];
  {
    const int rbv = row >> 8, rr = row & 255;
    const int w = rr >> 6, rr6 = rr & 63;
    const int rt = rr6 >> 4, q4 = (rr6 >> 2) & 3, i = rr6 & 3;
    const int ct = col >> 4, lane = q4 * 16 + (col & 15);
    const int base = ((rbv * 4 + w) * 8 + rt * 2 + ct) * 256 + lane * 4 + i;
#pragma unroll
    for (int k = 0; k < KSPLIT; ++k)
      s += __builtin_nontemporal_load(&P[(size_t)k * (NATOMS * DIM) + base]);
  }
  xs[off] = s;
  if (compute_h) {  // uniform branch
    xsl[r8][col] = s;
#pragma unroll
    for (int i = 0; i < 4; ++i) {
      const int idx = tid + i * 256;
      ((float*)Wl)[idx] = W[idx];
    }
    __syncthreads();
    float a = b[col];
#pragma unroll
    for (int d = 0; d < DIM; ++d) a += xsl[r8][d] * Wl[d][col];
    union { __hip_bfloat16 bb; ushort u; } cv;
    cv.bb = __float2bfloat16(fmaxf(a, 0.f));
    hT[(size_t)col * NATOMS + row] = cv.u;
  }
}

extern "C" void kernel_launch(void* const* d_in, const int* in_sizes, int n_in,
                              void* d_out, int out_size, void* d_ws, size_t ws_size,
                              hipStream_t stream) {
  const int*   fp    = (const int*)d_in[0];
  const float* adj   = (const float*)d_in[1];
  const int*   words = (const int*)d_in[2];
  const float* embfp = (const float*)d_in[3];
  const float* embw  = (const float*)d_in[4];
  const float* Wg    = (const float*)d_in[5];
  const float* bg    = (const float*)d_in[6];

  float* out = (float*)d_out;
  float* xs  = out;                 // [8192*32] final compound_vector
  float* wv  = out + NATOMS * DIM;  // [4096*32] word vectors

  float*  P   = (float*)d_ws;                               // 16 MB partials
  ushort* Abf = (ushort*)(P + (size_t)KSPLIT * NATOMS * DIM);  // 128 MB bf16 A
  ushort* hT  = Abf + (size_t)NATOMS * NATOMS;              // 512 KB bf16 h^T

  cpi_front<<<dim3(NATOMS / 8 + NSEQ * DIM / 256), dim3(256), 0, stream>>>(
      fp, embfp, Wg, bg, xs, hT, words, embw, wv);

  // layer 0: fp32 A staged (NT), bf16 MFMA, emits Abf tile image
  cpi_gemm1<<<dim3(512), dim3(256), 0, stream>>>(adj, hT, P, Abf);
  cpi_reduce_h<<<dim3(NATOMS / 8), dim3(256), 0, stream>>>(
      P, Wg + DIM * DIM, bg + DIM, xs, hT, 1);

  // layer 1: bf16 tile-image MFMA (Abf hot in Infinity Cache)
  cpi_gemm2<<<dim3(512), dim3(256), 0, stream>>>(Abf, hT, P);
  cpi_reduce_h<<<dim3(NATOMS / 8), dim3(256), 0, stream>>>(
      P, Wg + 2 * DIM * DIM, bg + 2 * DIM, xs, hT, 1);

  // layer 2: bf16 tile-image MFMA
  cpi_gemm2<<<dim3(512), dim3(256), 0, stream>>>(Abf, hT, P);
  cpi_reduce_h<<<dim3(NATOMS / 8), dim3(256), 0, stream>>>(
      P, Wg, bg, xs, hT, 0);
}